// Round 8
// baseline (383.562 us; speedup 1.0000x reference)
//
#include <hip/hip_runtime.h>

#define CI    32
#define IH    224
#define IW    224
#define OHS   220
#define OWS   220
#define NF    64
#define KS    5

// fallback-kernel macros
#define XCOLS 228
#define CP    36
#define WPD   40
#define XROWS 8
#define NBUFW (KS * NF * WPD)

// conv_t5 tile: 8 staged rows x 84 px x 32 c bf16 (4 oh x 80 ow output band)
#define BPX   80                 // output px per band
#define SPX   84                 // staged px per band (80 + 4 halo)
#define SCHK  (SPX * 4)          // 336 16B-chunks per staged row
#define SROWB (SCHK * 16)        // 5376 B per staged row
#define NRW   8

typedef __attribute__((ext_vector_type(4))) float   f32x4;
typedef __attribute__((ext_vector_type(4))) __bf16  bf16x4;
typedef __attribute__((ext_vector_type(8))) __bf16  bf16x8;

// Fused prep: x fp32 NCHW -> bf16 NHWC, plus (blocks 0..199) weight repack
// fp32 [f][c][kh][kw] -> bf16 [tap][f][c].
__global__ __launch_bounds__(256)
void prep_kernel(const float* __restrict__ x, const float* __restrict__ w,
                 __bf16* __restrict__ xh, __bf16* __restrict__ wp) {
  int chunk = blockIdx.x * 256 + threadIdx.x;   // 16*224*224*4 chunks of 8 channels
  int c8  = (chunk & 3) * 8;
  int pos = chunk >> 2;                         // n*50176 + h*224 + w
  int ww  = pos % IW;
  int nh  = pos / IW;
  int n   = nh / IH;
  int h   = nh - n * IH;
  const float* xp = x + ((size_t)n * CI + c8) * (IH * IW) + h * IW + ww;
  bf16x8 v;
#pragma unroll
  for (int j = 0; j < 8; ++j) v[j] = (__bf16)xp[(size_t)j * (IH * IW)];
  *(bf16x8*)(xh + (size_t)pos * CI + c8) = v;

  if (blockIdx.x < 200) {                       // 200*256 == 51200 exactly
    int i = blockIdx.x * 256 + threadIdx.x;
    int c   = i & (CI - 1);
    int f   = (i >> 5) & (NF - 1);
    int tap = i >> 11;
    int kh = tap / KS, kw = tap % KS;
    wp[i] = (__bf16)w[((f * CI + c) * KS + kh) * KS + kw];
  }
}

// Register-slim conv: block = 256 thr (4 waves) = 4 oh x 80 ow x 64 f band.
// 5 tiles/wave -> acc 80 regs (total ~164 <= 170) -> 3 waves/SIMD; stage
// 8 rows x 84 px = 43008 B LDS -> 3 blocks/CU. One-shot stage, one barrier,
// weights direct from global. 3 col-bands (0/80/160, last masked at 220).
__global__ __launch_bounds__(256, 3)
void conv_t5(const __bf16* __restrict__ xh, const __bf16* __restrict__ wp,
             const float* __restrict__ bias, float* __restrict__ out) {
  __shared__ __bf16 xs[NRW * SCHK * 8];   // 43008 B

  const int tid  = threadIdx.x;
  const int lane = tid & 63;
  const int wv   = tid >> 6;    // 0..3
  const int m    = lane & 15;   // MFMA col (pixel) / A row (filter)
  const int q    = lane >> 4;   // c-chunk / C row group

  const int bid  = blockIdx.x;
  const int lid  = (bid & 7) * 330 + (bid >> 3);  // bijection on [0,2640), 2640=8*330
  const int n    = lid / 165;
  const int rem  = lid - n * 165;
  const int band = rem % 3;
  const int oh0  = (rem / 3) * 4;                 // 0,4,...,216
  const int px0  = band * BPX;                    // 0,80,160

  // ---- one-shot stage: rows oh0..oh0+7, px [px0, px0+84) ----
  // band 2 tail reads past row end (next row / <=1280B into wp region after xh):
  // finite bf16, feeds only store-masked ow>=220 outputs.
  {
    const __bf16* xb = xh + (((size_t)n * IH + oh0) * IW + px0) * CI;
    for (int u = wv; u < 48; u += 4) {        // 8 rows x 6 units (5 full + 1 tail)
      int r = u / 6;
      int k = u - r * 6;
      int c = k * 64 + lane;                  // chunk within row (tail: lanes<16)
      if (k < 5 || lane < 16)
        __builtin_amdgcn_global_load_lds(
            (const __attribute__((address_space(1))) void*)(xb + (size_t)r * (IW * CI) + c * 8),
            (__attribute__((address_space(3))) void*)&xs[(r * SCHK + k * 64) * 8], 16, 0, 0);
    }
  }

  // per-wave tiles: t = wv + 4j over 20 = 4 rows x 5 col-tiles (5 per wave)
  int bbase[5];
#pragma unroll
  for (int j = 0; j < 5; ++j) {
    int t  = wv + j * 4;          // 0..19
    int rj = t / 5;               // output row offset 0..3
    int ct = t - rj * 5;          // col-tile 0..4
    bbase[j] = rj * SROWB + ((ct * 16 + m) * 4 + q) * 16;   // byte offset kh=kw=0
  }

  f32x4 acc[20];
#pragma unroll
  for (int i = 0; i < 20; ++i) { f32x4 z = {0.f, 0.f, 0.f, 0.f}; acc[i] = z; }

  const __bf16* wpl = wp + m * CI + q * 8;    // lane base into [tap][f][c]

  __syncthreads();

#pragma unroll
  for (int kh = 0; kh < KS; ++kh) {
    const int khb = kh * SROWB;
#pragma unroll
    for (int kw = 0; kw < KS; ++kw) {
      bf16x8 af[4];
#pragma unroll
      for (int ft = 0; ft < 4; ++ft)          // 1KB/wave coalesced, L1/L2-resident
        af[ft] = *(const bf16x8*)(wpl + (size_t)(kh * KS + kw) * (NF * CI) + ft * 16 * CI);
#pragma unroll
      for (int j = 0; j < 5; ++j) {
        bf16x8 bv = *(const bf16x8*)((const char*)xs + khb + bbase[j] + kw * 64);
#pragma unroll
        for (int ft = 0; ft < 4; ++ft)
          acc[j * 4 + ft] =
              __builtin_amdgcn_mfma_f32_16x16x32_bf16(af[ft], bv, acc[j * 4 + ft], 0, 0, 0);
      }
    }
  }

  // epilogue: C/D layout col=lane&15 (pixel), row=q*4+reg (filter within 16)
  float bvv[16];
#pragma unroll
  for (int ft = 0; ft < 4; ++ft)
#pragma unroll
    for (int rg = 0; rg < 4; ++rg)
      bvv[ft * 4 + rg] = bias[ft * 16 + q * 4 + rg];

#pragma unroll
  for (int j = 0; j < 5; ++j) {
    int t  = wv + j * 4;
    int rj = t / 5;
    int ct = t - rj * 5;
    int ow = px0 + ct * 16 + m;
    if (ow < OWS) {               // only band 2 masks (px 220..243)
      int oh = oh0 + rj;
#pragma unroll
      for (int ft = 0; ft < 4; ++ft)
#pragma unroll
        for (int rg = 0; rg < 4; ++rg) {
          int f = ft * 16 + q * 4 + rg;
          out[(((size_t)n * NF + f) * OHS + oh) * OWS + ow] =
              acc[j * 4 + ft][rg] + bvv[ft * 4 + rg];
        }
    }
  }
}

// ---------------- fallbacks (used only if ws too small) ----
__global__ void repack_w_kernel(const float* __restrict__ w, __bf16* __restrict__ wp) {
  int i = blockIdx.x * 256 + threadIdx.x;
  if (i >= KS * KS * NF * CI) return;
  int c   = i & (CI - 1);
  int f   = (i >> 5) & (NF - 1);
  int tap = i >> 11;
  int kh = tap / KS, kw = tap % KS;
  wp[i] = (__bf16)w[((f * CI + c) * KS + kh) * KS + kw];
}

template <bool USE_WS>
__global__ __launch_bounds__(512, 1)
void conv_main(const float* __restrict__ x, const float* __restrict__ w,
               const __bf16* __restrict__ wp, const float* __restrict__ bias,
               float* __restrict__ out) {
  __shared__ __bf16 xs[XROWS * XCOLS * CP];
  __shared__ __bf16 wsm[NBUFW];

  const int tid  = threadIdx.x;
  const int lane = tid & 63;
  const int wv   = tid >> 6;
  const int m    = lane & 15;
  const int q    = lane >> 4;

  int bid = blockIdx.x;
  int lid = (bid >> 3) + (bid & 7) * 110;
  const int n   = lid / 55;
  const int oh0 = (lid % 55) * 4;

  {
    const float* xn = x + (size_t)n * CI * IH * IW;
    for (int p = tid; p < XROWS * 56 * 8; p += 512) {
      int pc   = p & 7;
      int pg   = p >> 3;
      int pcol = pg % 56;
      int prow = pg / 56;
      int row  = oh0 + prow;
      f32x4 v0 = *(const f32x4*)(xn + ((size_t)(pc * 4 + 0) * IH + row) * IW + pcol * 4);
      f32x4 v1 = *(const f32x4*)(xn + ((size_t)(pc * 4 + 1) * IH + row) * IW + pcol * 4);
      f32x4 v2 = *(const f32x4*)(xn + ((size_t)(pc * 4 + 2) * IH + row) * IW + pcol * 4);
      f32x4 v3 = *(const f32x4*)(xn + ((size_t)(pc * 4 + 3) * IH + row) * IW + pcol * 4);
#pragma unroll
      for (int dcol = 0; dcol < 4; ++dcol) {
        bf16x4 t;
        t[0] = (__bf16)v0[dcol]; t[1] = (__bf16)v1[dcol];
        t[2] = (__bf16)v2[dcol]; t[3] = (__bf16)v3[dcol];
        *(bf16x4*)&xs[(prow * XCOLS + pcol * 4 + dcol) * CP + pc * 4] = t;
      }
    }
    for (int z = tid; z < XROWS * 4 * CP; z += 512) {
      int rr  = z / (4 * CP);
      int rem = z - rr * (4 * CP);
      xs[(rr * XCOLS + 224) * CP + rem] = (__bf16)0.0f;
    }
  }

  if (USE_WS) {
    for (int i = tid; i < NF * CI * KS / 8; i += 512) {
      int c0 = (i & 3) * 8;
      int f  = (i >> 2) & 63;
      int kw = i >> 8;
      bf16x8 v = *(const bf16x8*)(wp + ((size_t)(0 * KS + kw) * NF + f) * CI + c0);
      *(bf16x8*)&wsm[(kw * NF + f) * WPD + c0] = v;
    }
  } else {
    for (int i = tid; i < KS * NF * CI; i += 512) {
      int c  = i & 31;
      int f  = (i >> 5) & 63;
      int kw = i >> 11;
      wsm[(kw * NF + f) * WPD + c] = (__bf16)w[((f * CI + c) * KS + 0) * KS + kw];
    }
  }
  __syncthreads();

  int rj[7], cbj[7], xoff[7];
#pragma unroll
  for (int j = 0; j < 7; ++j) {
    int t   = wv + j * 8;
    rj[j]   = t / 14;
    cbj[j]  = (t % 14) * 16;
    xoff[j] = (rj[j] * XCOLS + cbj[j] + m) * CP + q * 8;
  }

  f32x4 acc[28];
#pragma unroll
  for (int i = 0; i < 28; ++i) { f32x4 z = {0.f, 0.f, 0.f, 0.f}; acc[i] = z; }

  for (int kh = 0; kh < KS; ++kh) {
    bf16x8 pw[3];
    if (USE_WS && kh < KS - 1) {
#pragma unroll
      for (int it = 0; it < 3; ++it) {
        int e = it * 512 + tid;
        if (e < 1280) {
          int c0 = (e & 3) * 8;
          int f  = (e >> 2) & 63;
          int kw = e >> 8;
          pw[it] = *(const bf16x8*)(wp + ((size_t)((kh + 1) * KS + kw) * NF + f) * CI + c0);
        }
      }
    }

#pragma unroll
    for (int kw = 0; kw < KS; ++kw) {
      bf16x8 af[4];
#pragma unroll
      for (int ft = 0; ft < 4; ++ft)
        af[ft] = *(const bf16x8*)&wsm[(kw * NF + ft * 16 + m) * WPD + q * 8];
#pragma unroll
      for (int j = 0; j < 7; ++j) {
        const __bf16* bp = &xs[xoff[j] + (kh * XCOLS + kw) * CP];
        bf16x4 lo = *(const bf16x4*)bp;
        bf16x4 hi = *(const bf16x4*)(bp + 4);
        bf16x8 bv8 = __builtin_shufflevector(lo, hi, 0, 1, 2, 3, 4, 5, 6, 7);
#pragma unroll
        for (int ft = 0; ft < 4; ++ft)
          acc[j * 4 + ft] =
              __builtin_amdgcn_mfma_f32_16x16x32_bf16(af[ft], bv8, acc[j * 4 + ft], 0, 0, 0);
      }
    }

    if (kh < KS - 1) {
      __syncthreads();
      if (USE_WS) {
#pragma unroll
        for (int it = 0; it < 3; ++it) {
          int e = it * 512 + tid;
          if (e < 1280) {
            int c0 = (e & 3) * 8;
            int f  = (e >> 2) & 63;
            int kw = e >> 8;
            *(bf16x8*)&wsm[(kw * NF + f) * WPD + c0] = pw[it];
          }
        }
      } else {
        for (int i = tid; i < KS * NF * CI; i += 512) {
          int c  = i & 31;
          int f  = (i >> 5) & 63;
          int kw = i >> 11;
          wsm[(kw * NF + f) * WPD + c] =
              (__bf16)w[((f * CI + c) * KS + (kh + 1)) * KS + kw];
        }
      }
      __syncthreads();
    }
  }

  float bvv[16];
#pragma unroll
  for (int ft = 0; ft < 4; ++ft)
#pragma unroll
    for (int rg = 0; rg < 4; ++rg)
      bvv[ft * 4 + rg] = bias[ft * 16 + q * 4 + rg];

#pragma unroll
  for (int j = 0; j < 7; ++j) {
    int ow = cbj[j] + m;
    if (ow < OWS) {
      int oh = oh0 + rj[j];
#pragma unroll
      for (int ft = 0; ft < 4; ++ft) {
#pragma unroll
        for (int rg = 0; rg < 4; ++rg) {
          int f = ft * 16 + q * 4 + rg;
          out[(((size_t)n * NF + f) * OHS + oh) * OWS + ow] = acc[j * 4 + ft][rg] + bvv[ft * 4 + rg];
        }
      }
    }
  }
}

extern "C" void kernel_launch(void* const* d_in, const int* in_sizes, int n_in,
                              void* d_out, int out_size, void* d_ws, size_t ws_size,
                              hipStream_t stream) {
  const float* x    = (const float*)d_in[0];
  const float* w    = (const float*)d_in[1];
  const float* bias = (const float*)d_in[2];
  float* out = (float*)d_out;

  const int    NW = KS * KS * NF * CI;                              // 51200
  const size_t WB = (size_t)NW * sizeof(__bf16);                    // 102400 B
  const size_t XB = (size_t)16 * IH * IW * CI * sizeof(__bf16);     // 51,380,224 B

  if (ws_size >= XB + WB) {
    // fast path: NHWC bf16 x first, repacked weights after it (stage tail
    // over-reads land in wp: finite bf16, store-masked outputs only)
    __bf16* xhp = (__bf16*)d_ws;
    __bf16* wp  = (__bf16*)((char*)d_ws + XB);
    prep_kernel<<<(16 * IH * IW * 4) / 256, 256, 0, stream>>>(x, w, xhp, wp);
    conv_t5<<<2640, 256, 0, stream>>>(xhp, wp, bias, out);
  } else if (ws_size >= WB) {
    __bf16* wp = (__bf16*)d_ws;
    repack_w_kernel<<<(NW + 255) / 256, 256, 0, stream>>>(w, wp);
    conv_main<true><<<880, 512, 0, stream>>>(x, w, wp, bias, out);
  } else {
    conv_main<false><<<880, 512, 0, stream>>>(x, w, nullptr, bias, out);
  }
}